// Round 14
// baseline (215.013 us; speedup 1.0000x reference)
//
#include <hip/hip_runtime.h>
#include <hip/hip_bf16.h>
#include <math.h>

#define Bv 64
#define Jv 20000
#define NBT 8      // b tiles (8 b each)
#define NYB 125    // y blocks; each processes ITERS j-tiles of 32 j
#define ITERS 5

typedef __attribute__((ext_vector_type(8))) short short8;
typedef __attribute__((ext_vector_type(4))) float f32x4;
typedef __attribute__((ext_vector_type(2))) float f32x2;
typedef __attribute__((ext_vector_type(2))) unsigned int u32x2;

union U8 { short8 s; unsigned int u[4]; };

__device__ __forceinline__ unsigned short f2bf(float f) {
  unsigned int u = __float_as_uint(f);
  u += 0x7FFFu + ((u >> 16) & 1u);
  return (unsigned short)(u >> 16);
}
__device__ __forceinline__ unsigned int pkbf(float a, float b) {
  __hip_bfloat162 h = __float22bfloat162_rn(make_float2(a, b));
  union { __hip_bfloat162 h; unsigned int u; } c;
  c.h = h;
  return c.u;  // a in low 16, b in high 16
}

// Packed f32 (VOP3P v_pk_fma_f32 / v_pk_max_f32): halves VALU instr count on
// element-wise chains; same IEEE fma per lane -> bit-identical results.
__device__ __forceinline__ f32x2 pk_fma(f32x2 a, f32x2 b, f32x2 c) {
  return __builtin_elementwise_fma(a, b, c);
}
__device__ __forceinline__ f32x2 pk_max0(f32x2 a) {
  f32x2 z = {0.f, 0.f};
  return __builtin_elementwise_max(a, z);
}

// DPP butterfly add (VALU pipe). 0xB1=xor1, 0x4E=xor2, 0x124=row_ror:4,
// 0x128=row_ror:8, 0x141=row_half_mirror.
template <int CTRL>
__device__ __forceinline__ float dppadd(float v) {
  int t = __builtin_amdgcn_update_dpp(0, __float_as_int(v), CTRL, 0xF, 0xF, true);
  return v + __int_as_float(t);
}
// Hardened permlane sums (R3 lesson: tied-operand aliasing) — distinct
// early-clobber second reg initialized inside the asm.
__device__ __forceinline__ float pl16sum(float v) {
  float a = v, b;
  asm("v_mov_b32 %1, %0\n\t"
      "v_permlane16_swap_b32 %0, %1"
      : "+v"(a), "=&v"(b));
  return a + b;
}
__device__ __forceinline__ float pl32sum(float v) {
  float a = v, b;
  asm("v_mov_b32 %1, %0\n\t"
      "v_permlane32_swap_b32 %0, %1"
      : "+v"(a), "=&v"(b));
  return a + b;
}

// Block = 32 j x 8 b per tile, 5 tiles per block (grid 8 x 125) — R12 champion.
// R13/R14: XOR bank swizzle on s_h / s_pair keyed on ((row>>6)&3) (32B
// granularity). P4/P5/pair accesses have row>>6 == wv (wave-uniform shift);
// P6 rows have row>>6 == quad -> quads hit 4 disjoint bank octets (was 8-way
// bh / 4-way e conflicts: quad strides 4608B/1024B = 0 mod 128B).
// R14 fix: vectorized access under XOR swizzle requires (base+k)^key ==
// (base^key)+k over the span — P5's 8-ushort h-load had base&15 == 12 cases
// carrying into the key bits (absmax 0.0625). Split into two independently
// XOR-addressed 8B loads (span 3, base&15 <= 12: never carries).
__global__ __launch_bounds__(256, 2) void pe_fused(
    const float* __restrict__ x, const int* __restrict__ mask,
    const int* __restrict__ atse_idx, const float* __restrict__ fe,
    const float* __restrict__ ae,
    const float* __restrict__ hW1, const float* __restrict__ hb1,
    const float* __restrict__ hl1g, const float* __restrict__ hl1b,
    const float* __restrict__ hW2, const float* __restrict__ hb2,
    const float* __restrict__ hl2g, const float* __restrict__ hl2b,
    const float* __restrict__ gW1, const float* __restrict__ gb1,
    const float* __restrict__ gW2, const float* __restrict__ gb2,
    float* __restrict__ acc_g, float* __restrict__ se_g) {
  __shared__ __align__(16) float s_pg[32 * 68];      // pre1; cols 64..67 = ex scratch
  __shared__ __align__(16) float s_gb[32 * 24 + 16]; // gate bias per j
  __shared__ __align__(16) float s_pair[256 * 4];    // pair scalars / e; prologue: gW1bf
  __shared__ __align__(16) float s_ae[32 * 20];      // ae rows (dedicated)
  __shared__ __align__(16) float s_w0[64], s_w0g[64], s_l1g[64], s_l1b[64];
  __shared__ __align__(16) float s_b2[32], s_l2g[32], s_l2b[32];
  __shared__ __align__(16) float s_gb1[24], s_gW2[96];
  __shared__ float s_gb2[4], s_scal[2];
  __shared__ __align__(16) float s_gW1aT[24 * 16];   // gW1 ae-part, [c][a] transposed
  __shared__ unsigned char s_mk[256];
  __shared__ __align__(16) unsigned short s_ovl[256 * 36];  // s_h bf16 [256][36]

  int tid = threadIdx.x;
  int btile = blockIdx.x;   // 0..7
  int ytile = blockIdx.y;   // 0..124
  int lane = tid & 63, wv = tid >> 6;
  int li = lane & 15, quad = lane >> 4;
  unsigned short* s_h = s_ovl;
  unsigned short* s_gW1bf = (unsigned short*)s_pair;  // prologue-only overlay
  // swizzle constants: ((row>>6)&3)<<4 ushorts / <<3 floats — row>>6 is wv for
  // all P4/P5/pair accesses, quad for all P6 accesses (verified: low bits <64).
  int hswz = wv << 4;    // s_h (ushort idx), own-wave rows
  int eswz = wv << 3;    // s_pair (float idx), own-wave rows
  int hswzq = quad << 4; // s_h, P6 rows (row = quad*64 + ...)
  int eswzq = quad << 3; // s_pair, P6 rows

  // ---------------- prologue: stage persistent weights ----------------
  for (int i = tid; i < 768; i += 256) s_gW1bf[i] = f2bf(gW1[i]);
  for (int i = tid; i < 384; i += 256)
    s_gW1aT[i] = gW1[768 + (i & 15) * 24 + (i >> 4)];
  if (tid < 96) s_gW2[tid] = gW2[tid];
  if (tid < 64) { s_w0[tid] = hW1[tid]; s_l1g[tid] = hl1g[tid]; s_l1b[tid] = hl1b[tid]; }
  if (tid < 32) { s_b2[tid] = hb2[tid]; s_l2g[tid] = hl2g[tid]; s_l2b[tid] = hl2b[tid]; }
  if (tid < 24) s_gb1[tid] = gb1[tid];
  if (tid < 4) s_gb2[tid] = gb2[tid];
  if (tid >= 224 && tid < 240) s_gb[32 * 24 + (tid - 224)] = 0.f;  // overhang zeros

  // per-thread register fragments (j-independent)
  short8 bW2[2][2];
#pragma unroll
  for (int kt = 0; kt < 2; ++kt)
#pragma unroll
    for (int nt = 0; nt < 2; ++nt) {
      U8 t;
#pragma unroll
      for (int p = 0; p < 4; ++p) {
        float lo = hW2[(kt * 32 + quad * 8 + 2 * p) * 32 + nt * 16 + li];
        float hi = hW2[(kt * 32 + quad * 8 + 2 * p + 1) * 32 + nt * 16 + li];
        t.u[p] = pkbf(lo, hi);
      }
      bW2[kt][nt] = t.s;
    }
  U8 bH;
#pragma unroll
  for (int p = 0; p < 4; ++p) {
    float lo = hW1[(1 + quad * 8 + 2 * p) * 64 + wv * 16 + li];
    float hi = hW1[(1 + quad * 8 + 2 * p + 1) * 64 + wv * 16 + li];
    bH.u[p] = pkbf(lo, hi);
  }
  float hb = hb1[wv * 16 + li];

  __syncthreads();
  if (tid < 64) s_w0g[tid] = s_w0[tid] * s_l1g[tid];
  if (tid == 64) {
    float sw = 0.f, qw = 0.f;
    for (int k = 0; k < 64; ++k) { float w = s_w0[k]; sw += w; qw = fmaf(w, w, qw); }
    s_scal[0] = sw; s_scal[1] = qw;
  }
  // gate A-frags from s_gW1bf overlay (read pre-bar1; s_pair written post-bar1)
  short8 aG0, aG1;
#pragma unroll
  for (int i = 0; i < 8; ++i) {
    int k = quad * 8 + i;
    aG0[i] = (short)s_gW1bf[k * 24 + li];
    aG1[i] = (li < 8) ? (short)s_gW1bf[k * 24 + 16 + li] : (short)0;
  }

  f32x4 racc[2][2];
#pragma unroll
  for (int a = 0; a < 2; ++a)
#pragma unroll
    for (int c = 0; c < 2; ++c) {
      racc[a][c][0] = 0.f; racc[a][c][1] = 0.f; racc[a][c][2] = 0.f; racc[a][c][3] = 0.f;
    }
  float seacc[2] = {0.f, 0.f};

  int jp8 = tid >> 3, b8 = tid & 7;
  int J0 = ytile * ITERS * 32;
  float xv; int mk;

  // ---------------- A(0): ae gather + x/mask + pre1 MFMA ----------------
  {
    if (tid < 128) {
      int jj = tid >> 2, q = tid & 3;
      int ai = atse_idx[J0 + jj];
      float4 av = *(const float4*)(ae + (size_t)ai * 16 + q * 4);
      *(float4*)(s_ae + jj * 20 + q * 4) = av;
    }
    size_t xo = (size_t)(btile * 8 + b8) * Jv + J0 + jp8;
    xv = x[xo];
    mk = mask[xo];
    f32x4 cP;
#pragma unroll
    for (int mt = 0; mt < 2; ++mt) {
      cP[0] = hb; cP[1] = hb; cP[2] = hb; cP[3] = hb;
      const float* fp = fe + (size_t)(J0 + mt * 16 + li) * 32 + quad * 8;
      float4 f0 = *(const float4*)fp;
      float4 f1 = *(const float4*)(fp + 4);
      U8 aF;
      aF.u[0] = pkbf(f0.x, f0.y); aF.u[1] = pkbf(f0.z, f0.w);
      aF.u[2] = pkbf(f1.x, f1.y); aF.u[3] = pkbf(f1.z, f1.w);
      cP = __builtin_amdgcn_mfma_f32_16x16x32_bf16(aF.s, bH.s, cP, 0, 0, 0);
#pragma unroll
      for (int r = 0; r < 4; ++r)
        s_pg[(mt * 16 + quad * 4 + r) * 68 + wv * 16 + li] = cP[r];
    }
  }
  __syncthreads();  // bar1

  for (int it = 0; it < ITERS; ++it) {
    // -------- B: gate bias + stats + pair scalars + P4 + P5 --------
    {
      int c0 = b8 * 3;
      const f32x2* ar2 = (const f32x2*)(s_ae + jp8 * 20);
      f32x2 A[8];
#pragma unroll
      for (int a = 0; a < 8; ++a) A[a] = ar2[a];
#pragma unroll
      for (int c = 0; c < 3; ++c) {
        const f32x2* tr2 = (const f32x2*)(s_gW1aT + (c0 + c) * 16);
        f32x2 g2 = {s_gb1[c0 + c], 0.f};
#pragma unroll
        for (int a = 0; a < 8; ++a) g2 = pk_fma(A[a], tr2[a], g2);
        s_gb[jp8 * 24 + c0 + c] = g2.x + g2.y;
      }
    }
    {
      const f32x2* pp2 = (const f32x2*)(s_pg + jp8 * 68 + b8 * 8);
      const f32x2* ww2 = (const f32x2*)(s_w0 + b8 * 8);
      f32x2 p2[4] = {pp2[0], pp2[1], pp2[2], pp2[3]};
      f32x2 s2 = (p2[0] + p2[1]) + (p2[2] + p2[3]);
      f32x2 q2 = pk_fma(p2[0], p2[0],
                 pk_fma(p2[1], p2[1],
                 pk_fma(p2[2], p2[2], p2[3] * p2[3])));
      f32x2 d2 = pk_fma(p2[0], ww2[0],
                 pk_fma(p2[1], ww2[1],
                 pk_fma(p2[2], ww2[2], p2[3] * ww2[3])));
      float sp = s2.x + s2.y, qp = q2.x + q2.y, dwp = d2.x + d2.y;
      sp = dppadd<0xB1>(sp); sp = dppadd<0x4E>(sp); sp = dppadd<0x141>(sp);
      qp = dppadd<0xB1>(qp); qp = dppadd<0x4E>(qp); qp = dppadd<0x141>(qp);
      dwp = dppadd<0xB1>(dwp); dwp = dppadd<0x4E>(dwp); dwp = dppadd<0x141>(dwp);
      if (b8 == 0) *(float4*)(s_pg + jp8 * 68 + 64) = make_float4(sp, qp, dwp, 0.f);
    }
    {
      float4 exv = *(const float4*)(s_pg + jp8 * 68 + 64);
      float mu1 = fmaf(xv, s_scal[0], exv.x) * 0.015625f;
      float Et2 = fmaf(xv * xv, s_scal[1], fmaf(2.0f * xv, exv.z, exv.y)) * 0.015625f;
      float rs1 = rsqrtf(fmaxf(Et2 - mu1 * mu1, 0.f) + 1e-5f);
      *(float4*)(s_pair + ((tid * 4) ^ eswz)) = make_float4(xv * rs1, rs1, -mu1 * rs1, 0.f);
      s_mk[tid] = (unsigned char)mk;
    }

    // P4: a-frags -> MFMA h2 -> LN2 -> s_h
    {
      f32x4 cd[4][2];
      float b2a = s_b2[li], b2b = s_b2[16 + li];
#pragma unroll
      for (int t = 0; t < 4; ++t) {
        cd[t][0][0] = b2a; cd[t][0][1] = b2a; cd[t][0][2] = b2a; cd[t][0][3] = b2a;
        cd[t][1][0] = b2b; cd[t][1][1] = b2b; cd[t][1][2] = b2b; cd[t][1][3] = b2b;
      }
      __builtin_amdgcn_s_setprio(1);  // T5: favor compute cluster vs other blocks
#pragma unroll
      for (int kt = 0; kt < 2; ++kt) {
        int base = kt * 32 + quad * 8;
        float4 wg0 = *(const float4*)(s_w0g + base);
        float4 wg1 = *(const float4*)(s_w0g + base + 4);
        float4 gg0 = *(const float4*)(s_l1g + base);
        float4 gg1 = *(const float4*)(s_l1g + base + 4);
        float4 bb0 = *(const float4*)(s_l1b + base);
        float4 bb1 = *(const float4*)(s_l1b + base + 4);
        f32x2 wg2[4] = {{wg0.x, wg0.y}, {wg0.z, wg0.w}, {wg1.x, wg1.y}, {wg1.z, wg1.w}};
        f32x2 gg2[4] = {{gg0.x, gg0.y}, {gg0.z, gg0.w}, {gg1.x, gg1.y}, {gg1.z, gg1.w}};
        f32x2 bb2[4] = {{bb0.x, bb0.y}, {bb0.z, bb0.w}, {bb1.x, bb1.y}, {bb1.z, bb1.w}};
#pragma unroll
        for (int t = 0; t < 4; ++t) {
          int mrow = wv * 64 + t * 16 + li;
          float4 pr = *(const float4*)(s_pair + ((mrow * 4) ^ eswz));
          f32x2 prx = {pr.x, pr.x}, pry = {pr.y, pr.y}, prz = {pr.z, pr.z};
          const float* pgp = s_pg + (mrow >> 3) * 68 + base;
          float4 p0 = *(const float4*)pgp;
          float4 p1 = *(const float4*)(pgp + 4);
          f32x2 pv2[4] = {{p0.x, p0.y}, {p0.z, p0.w}, {p1.x, p1.y}, {p1.z, p1.w}};
          U8 a8;
#pragma unroll
          for (int i = 0; i < 4; ++i) {
            f32x2 av2 = pk_max0(pk_fma(pk_fma(pry, pv2[i], prz), gg2[i],
                                       pk_fma(prx, wg2[i], bb2[i])));
            a8.u[i] = pkbf(av2.x, av2.y);
          }
          cd[t][0] = __builtin_amdgcn_mfma_f32_16x16x32_bf16(a8.s, bW2[kt][0], cd[t][0], 0, 0, 0);
          cd[t][1] = __builtin_amdgcn_mfma_f32_16x16x32_bf16(a8.s, bW2[kt][1], cd[t][1], 0, 0, 0);
        }
      }
      __builtin_amdgcn_s_setprio(0);
      float g0 = s_l2g[li], be0 = s_l2b[li];
      float g1v = s_l2g[16 + li], be1 = s_l2b[16 + li];
#pragma unroll
      for (int t = 0; t < 4; ++t) {
        float sum[4], sq[4];
#pragma unroll
        for (int r = 0; r < 4; ++r) {
          float a = cd[t][0][r], b = cd[t][1][r];
          sum[r] = a + b;
          sq[r] = fmaf(a, a, b * b);
        }
#pragma unroll
        for (int r = 0; r < 4; ++r) {
          sum[r] = dppadd<0xB1>(sum[r]); sum[r] = dppadd<0x4E>(sum[r]);
          sum[r] = dppadd<0x124>(sum[r]); sum[r] = dppadd<0x128>(sum[r]);
          sq[r] = dppadd<0xB1>(sq[r]); sq[r] = dppadd<0x4E>(sq[r]);
          sq[r] = dppadd<0x124>(sq[r]); sq[r] = dppadd<0x128>(sq[r]);
        }
#pragma unroll
        for (int r = 0; r < 4; ++r) {
          float mu = sum[r] * 0.03125f;
          float var = sq[r] * 0.03125f - mu * mu;
          float rs2 = rsqrtf(fmaxf(var, 0.f) + 1e-5f);
          int m = wv * 64 + t * 16 + quad * 4 + r;
          float h0 = fmaxf(fmaf((cd[t][0][r] - mu) * rs2, g0, be0), 0.f);
          float h1 = fmaxf(fmaf((cd[t][1][r] - mu) * rs2, g1v, be1), 0.f);
          s_h[(m * 36 + li) ^ hswz] = f2bf(h0);
          s_h[(m * 36 + 16 + li) ^ hswz] = f2bf(h1);
        }
      }
    }
    // no barrier: P5 touches only own-wave rows (in-order DS)

    // P5: gate via MFMA + packed combine + permlane quad-reduce
    {
      float4 gw4[2][4];
#pragma unroll
      for (int mt = 0; mt < 2; ++mt)
#pragma unroll
        for (int r = 0; r < 4; ++r) {
          int c = mt * 16 + quad * 4 + r;
          gw4[mt][r] = (c < 24) ? ((const float4*)s_gW2)[c]
                                : make_float4(0.f, 0.f, 0.f, 0.f);
        }
      __builtin_amdgcn_s_setprio(1);
#pragma unroll
      for (int nt = 0; nt < 4; ++nt) {
        int m = wv * 64 + nt * 16 + li;
        U8 bu;
        // R14: two independently swizzle-addressed 8B loads (span-3 safe)
        const u32x2* hpA = (const u32x2*)(s_h + ((m * 36 + quad * 8) ^ hswz));
        const u32x2* hpB = (const u32x2*)(s_h + ((m * 36 + quad * 8 + 4) ^ hswz));
        u32x2 h01 = hpA[0], h23 = hpB[0];
        bu.u[0] = h01[0]; bu.u[1] = h01[1]; bu.u[2] = h23[0]; bu.u[3] = h23[1];
        int j = m >> 3;
        float4 cc0 = *(const float4*)(s_gb + j * 24 + quad * 4);
        float4 cc1 = *(const float4*)(s_gb + j * 24 + 16 + quad * 4);
        f32x4 c0, c1;
        c0[0] = cc0.x; c0[1] = cc0.y; c0[2] = cc0.z; c0[3] = cc0.w;
        c1[0] = cc1.x; c1[1] = cc1.y; c1[2] = cc1.z; c1[3] = cc1.w;
        c0 = __builtin_amdgcn_mfma_f32_16x16x32_bf16(aG0, bu.s, c0, 0, 0, 0);
        c1 = __builtin_amdgcn_mfma_f32_16x16x32_bf16(aG1, bu.s, c1, 0, 0, 0);
        f32x2 r01 = {s_gb2[0], s_gb2[1]};
        f32x2 r23 = {s_gb2[2], s_gb2[3]};
#pragma unroll
        for (int r = 0; r < 4; ++r) {
          float v0 = fmaxf(c0[r], 0.f);
          float v1 = fmaxf(c1[r], 0.f);
          f32x2 v0b = {v0, v0}, v1b = {v1, v1};
          float4 ga = gw4[0][r], gb = gw4[1][r];
          f32x2 ga01 = {ga.x, ga.y}, ga23 = {ga.z, ga.w};
          f32x2 gb01 = {gb.x, gb.y}, gb23 = {gb.z, gb.w};
          r01 = pk_fma(v0b, ga01, pk_fma(v1b, gb01, r01));
          r23 = pk_fma(v0b, ga23, pk_fma(v1b, gb23, r23));
        }
        float r0 = pl32sum(pl16sum(r01.x));
        float r1 = pl32sum(pl16sum(r01.y));
        float r2 = pl32sum(pl16sum(r23.x));
        float r3 = pl32sum(pl16sum(r23.y));
        r0 = fminf(fmaxf(r0, -10.f), 10.f);
        r1 = fminf(fmaxf(r1, -10.f), 10.f);
        r2 = fminf(fmaxf(r2, -10.f), 10.f);
        r3 = fminf(fmaxf(r3, -10.f), 10.f);
        bool act = (s_mk[m] != 0);
        float e0 = act ? __expf(r0 - 10.f) : 0.f;
        float e1 = act ? __expf(r1 - 10.f) : 0.f;
        float e2 = act ? __expf(r2 - 10.f) : 0.f;
        float e3 = act ? __expf(r3 - 10.f) : 0.f;
        if (quad == 0) *(float4*)(s_pair + ((m * 4) ^ eswz)) = make_float4(e0, e1, e2, e3);
      }
      __builtin_amdgcn_s_setprio(0);
    }
    __syncthreads();  // bar2: e + s_h visible cross-wave

    // -------- P6(t) with A(t+1) pipelined into the slot --------
    bool has_next = (it + 1 < ITERS);
    int J0n = J0 + 32;
    float4 nf0, nf1, nav;
    float nxv = 0.f; int nmk = 0;
    if (has_next) {
      if (tid < 128) {
        int jj = tid >> 2, q = tid & 3;
        int ai = atse_idx[J0n + jj];
        nav = *(const float4*)(ae + (size_t)ai * 16 + q * 4);
      }
      const float* fp0 = fe + (size_t)(J0n + li) * 32 + quad * 8;
      nf0 = *(const float4*)fp0; nf1 = *(const float4*)(fp0 + 4);
      size_t xo = (size_t)(btile * 8 + b8) * Jv + J0n + jp8;
      nxv = x[xo];
      nmk = mask[xo];
    }
    // P6: e-h reduce via MFMA (rows = quad*64+... -> swizzle key is quad)
    {
      const float* s_e2 = s_pair;
#pragma unroll
      for (int bs = 0; bs < 2; ++bs) {
        int b = wv * 2 + bs;
        float ev[8];
        float sep = 0.f;
#pragma unroll
        for (int i = 0; i < 8; ++i) {
          int er = (quad * 8 + i) * 8 + b;
          float v = s_e2[(er * 4 + (li & 3)) ^ eswzq];
          v = (li < 4) ? v : 0.f;
          ev[i] = v;
          sep += v;
        }
        seacc[bs] += sep;
        U8 a8;
        a8.u[0] = pkbf(ev[0], ev[1]); a8.u[1] = pkbf(ev[2], ev[3]);
        a8.u[2] = pkbf(ev[4], ev[5]); a8.u[3] = pkbf(ev[6], ev[7]);
#pragma unroll
        for (int half = 0; half < 2; ++half) {
          U8 bh;
#pragma unroll
          for (int p = 0; p < 4; ++p) {
            unsigned int lo = s_h[(((quad * 8 + 2 * p) * 8 + b) * 36 + half * 16 + li) ^ hswzq];
            unsigned int hi = s_h[(((quad * 8 + 2 * p + 1) * 8 + b) * 36 + half * 16 + li) ^ hswzq];
            bh.u[p] = lo | (hi << 16);
          }
          racc[bs][half] = __builtin_amdgcn_mfma_f32_16x16x32_bf16(a8.s, bh.s, racc[bs][half], 0, 0, 0);
        }
      }
    }
    if (has_next) {
      if (tid < 128) {
        int jj = tid >> 2, q = tid & 3;
        *(float4*)(s_ae + jj * 20 + q * 4) = nav;
      }
      // issue second fe half now; latency overlaps s_ae write + mt=0 MFMA
      const float* fp1 = fe + (size_t)(J0n + 16 + li) * 32 + quad * 8;
      float4 nf2 = *(const float4*)fp1;
      float4 nf3 = *(const float4*)(fp1 + 4);
      f32x4 cP;
#pragma unroll
      for (int mt = 0; mt < 2; ++mt) {
        cP[0] = hb; cP[1] = hb; cP[2] = hb; cP[3] = hb;
        U8 aF;
        if (mt == 0) {
          aF.u[0] = pkbf(nf0.x, nf0.y); aF.u[1] = pkbf(nf0.z, nf0.w);
          aF.u[2] = pkbf(nf1.x, nf1.y); aF.u[3] = pkbf(nf1.z, nf1.w);
        } else {
          aF.u[0] = pkbf(nf2.x, nf2.y); aF.u[1] = pkbf(nf2.z, nf2.w);
          aF.u[2] = pkbf(nf3.x, nf3.y); aF.u[3] = pkbf(nf3.z, nf3.w);
        }
        cP = __builtin_amdgcn_mfma_f32_16x16x32_bf16(aF.s, bH.s, cP, 0, 0, 0);
#pragma unroll
        for (int r = 0; r < 4; ++r)
          s_pg[(mt * 16 + quad * 4 + r) * 68 + wv * 16 + li] = cP[r];
      }
      xv = nxv; mk = nmk;
      J0 = J0n;
      __syncthreads();  // bar3: A(t+1) visible + P6(t) reads done
    }
  }

  // ---------------- flush: one atomic pass per block ----------------
#pragma unroll
  for (int bs = 0; bs < 2; ++bs) {
    float se = seacc[bs];
    se = pl32sum(pl16sum(se));
    if (quad == 0) {
      int bg = btile * 8 + wv * 2 + bs;
      float* dst = acc_g + (size_t)bg * 128;
#pragma unroll
      for (int half = 0; half < 2; ++half)
#pragma unroll
        for (int r = 0; r < 4; ++r)
          atomicAdd(dst + r * 32 + half * 16 + li, racc[bs][half][r]);
      if (li < 4) atomicAdd(&se_g[bg * 4 + li], se);
    }
  }
}

// ---------------- per-b tail (R8): 256 threads, parallel matvecs ----------
__global__ __launch_bounds__(256) void pe_tail(
    const float* __restrict__ acc_g, const float* __restrict__ se_g,
    const float* __restrict__ cW, const float* __restrict__ cb,
    const float* __restrict__ clng, const float* __restrict__ clnb,
    const float* __restrict__ eW1, const float* __restrict__ eb1,
    const float* __restrict__ eW2, const float* __restrict__ eb2,
    float* __restrict__ out) {
  int b = blockIdx.x;
  int tid = threadIdx.x;
  __shared__ float s_hs[128], s_cp[32], s_comb[32], s_e1[128], s_o2[64];
  __shared__ float s_red[4];

  float se0 = se_g[b * 4 + 0];
  bool empty = !(se0 > 0.0f);
  if (tid < 128) {
    float sw = se_g[b * 4 + (tid >> 5)];
    float inv = empty ? 0.0f : 1.0f / sw;
    s_hs[tid] = acc_g[b * 128 + tid] * inv;
  }
  __syncthreads();

  // c-layer: 32 outputs x 128 terms; 8 threads/output, 16 terms each
  {
    int o = tid >> 3, seg = tid & 7;
    float p = 0.f;
#pragma unroll
    for (int i = 0; i < 16; ++i) {
      int k = seg * 16 + i;
      p = fmaf(s_hs[k], cW[k * 32 + o], p);
    }
    p += __shfl_xor(p, 1);
    p += __shfl_xor(p, 2);
    p += __shfl_xor(p, 4);
    if (seg == 0) s_cp[o] = p + cb[o];
  }
  __syncthreads();

  // c LN (affine) + relu over 32 outputs (lanes 0..31 of wave 0)
  if (tid < 32) {
    float cp = s_cp[tid];
    float ssum = cp;
#pragma unroll
    for (int off = 16; off > 0; off >>= 1) ssum += __shfl_xor(ssum, off, 32);
    float mu = ssum * (1.0f / 32.0f);
    float dd = cp - mu;
    float sq = dd * dd;
#pragma unroll
    for (int off = 16; off > 0; off >>= 1) sq += __shfl_xor(sq, off, 32);
    float rs = rsqrtf(sq * (1.0f / 32.0f) + 1e-5f);
    float comb = fmaxf(fmaf(dd * rs, clng[tid], clnb[tid]), 0.0f);
    if (empty) comb = 0.0f;
    s_comb[tid] = comb;
  }
  __syncthreads();

  // e1: 128 outputs x 32 terms; one thread per output (tid<128)
  float v1 = 0.f;
  if (tid < 128) {
    v1 = eb1[tid];
#pragma unroll
    for (int i = 0; i < 32; ++i) v1 = fmaf(s_comb[i], eW1[i * 128 + tid], v1);
    float ss = v1, sq = v1 * v1;
#pragma unroll
    for (int off = 32; off > 0; off >>= 1) {
      ss += __shfl_xor(ss, off);
      sq += __shfl_xor(sq, off);
    }
    if ((tid & 63) == 0) {
      s_red[(tid >> 6) * 2] = ss;
      s_red[(tid >> 6) * 2 + 1] = sq;
    }
  }
  __syncthreads();
  if (tid < 128) {
    float ssT = s_red[0] + s_red[2];
    float sqT = s_red[1] + s_red[3];
    float mu = ssT * (1.0f / 128.0f);
    float var = sqT * (1.0f / 128.0f) - mu * mu;
    float rs = rsqrtf(fmaxf(var, 0.f) + 1e-5f);
    s_e1[tid] = fmaxf((v1 - mu) * rs, 0.0f);
  }
  __syncthreads();

  // e2: 64 outputs x 128 terms; 4 threads/output, 32 terms each
  {
    int o = tid >> 2, sg = tid & 3;
    float v = 0.f;
#pragma unroll
    for (int i = 0; i < 32; ++i) {
      int k = sg * 32 + i;
      v = fmaf(s_e1[k], eW2[k * 64 + o], v);
    }
    v += __shfl_xor(v, 1);
    v += __shfl_xor(v, 2);
    if (sg == 0) s_o2[o] = v + eb2[o];
  }
  __syncthreads();

  // final LN (no affine) + relu over 64 + store (wave 0)
  if (tid < 64) {
    float v = s_o2[tid];
    float ss = v, sq = v * v;
#pragma unroll
    for (int off = 32; off > 0; off >>= 1) {
      ss += __shfl_xor(ss, off);
      sq += __shfl_xor(sq, off);
    }
    float mu = ss * (1.0f / 64.0f);
    float var = sq * (1.0f / 64.0f) - mu * mu;
    float rs = rsqrtf(fmaxf(var, 0.f) + 1e-5f);
    float o = fmaxf((v - mu) * rs, 0.0f);
    if (tid < 32)
      out[b * 32 + tid] = o;                       // mu
    else
      out[Bv * 32 + b * 32 + (tid - 32)] = o;      // logvar
  }
}

extern "C" void kernel_launch(void* const* d_in, const int* in_sizes, int n_in,
                              void* d_out, int out_size, void* d_ws, size_t ws_size,
                              hipStream_t stream) {
  const float* x    = (const float*)d_in[0];
  const int* mask   = (const int*)d_in[1];
  const int* atse   = (const int*)d_in[2];
  const float* fe   = (const float*)d_in[3];
  const float* ae   = (const float*)d_in[4];
  const float* hW1  = (const float*)d_in[5];
  const float* hb1  = (const float*)d_in[6];
  const float* hl1g = (const float*)d_in[7];
  const float* hl1b = (const float*)d_in[8];
  const float* hW2  = (const float*)d_in[9];
  const float* hb2  = (const float*)d_in[10];
  const float* hl2g = (const float*)d_in[11];
  const float* hl2b = (const float*)d_in[12];
  const float* gW1  = (const float*)d_in[13];
  const float* gb1  = (const float*)d_in[14];
  const float* gW2  = (const float*)d_in[15];
  const float* gb2  = (const float*)d_in[16];
  const float* cW   = (const float*)d_in[17];
  const float* cb   = (const float*)d_in[18];
  const float* clng = (const float*)d_in[19];
  const float* clnb = (const float*)d_in[20];
  const float* eW1  = (const float*)d_in[21];
  const float* eb1  = (const float*)d_in[22];
  const float* eW2  = (const float*)d_in[23];
  const float* eb2  = (const float*)d_in[24];
  float* out = (float*)d_out;

  float* ws = (float*)d_ws;
  float* accg = ws;                 // B*128 floats
  float* seg  = accg + Bv * 128;    // B*4 floats

  hipMemsetAsync(accg, 0, (Bv * 128 + Bv * 4) * sizeof(float), stream);

  pe_fused<<<dim3(NBT, NYB), dim3(256), 0, stream>>>(
      x, mask, atse, fe, ae, hW1, hb1, hl1g, hl1b, hW2, hb2, hl2g, hl2b,
      gW1, gb1, gW2, gb2, accg, seg);
  pe_tail<<<dim3(Bv), dim3(256), 0, stream>>>(
      accg, seg, cW, cb, clng, clnb, eW1, eb1, eW2, eb2, out);
}

// Round 15
// 196.485 us; speedup vs baseline: 1.0943x; 1.0943x over previous
//
#include <hip/hip_runtime.h>
#include <hip/hip_bf16.h>
#include <math.h>

#define Bv 64
#define Jv 20000
#define NBT 8      // b tiles (8 b each)
#define NYB 125    // y blocks; each processes ITERS j-tiles of 32 j
#define ITERS 5

typedef __attribute__((ext_vector_type(8))) short short8;
typedef __attribute__((ext_vector_type(4))) float f32x4;
typedef __attribute__((ext_vector_type(2))) float f32x2;
typedef __attribute__((ext_vector_type(2))) unsigned int u32x2;

union U8 { short8 s; unsigned int u[4]; };

__device__ __forceinline__ unsigned short f2bf(float f) {
  unsigned int u = __float_as_uint(f);
  u += 0x7FFFu + ((u >> 16) & 1u);
  return (unsigned short)(u >> 16);
}
__device__ __forceinline__ unsigned int pkbf(float a, float b) {
  __hip_bfloat162 h = __float22bfloat162_rn(make_float2(a, b));
  union { __hip_bfloat162 h; unsigned int u; } c;
  c.h = h;
  return c.u;  // a in low 16, b in high 16
}

// Packed f32 (VOP3P v_pk_fma_f32 / v_pk_max_f32): halves VALU instr count on
// element-wise chains; same IEEE fma per lane -> bit-identical results.
__device__ __forceinline__ f32x2 pk_fma(f32x2 a, f32x2 b, f32x2 c) {
  return __builtin_elementwise_fma(a, b, c);
}
__device__ __forceinline__ f32x2 pk_max0(f32x2 a) {
  f32x2 z = {0.f, 0.f};
  return __builtin_elementwise_max(a, z);
}

// DPP butterfly add (VALU pipe). 0xB1=xor1, 0x4E=xor2, 0x124=row_ror:4,
// 0x128=row_ror:8, 0x141=row_half_mirror.
template <int CTRL>
__device__ __forceinline__ float dppadd(float v) {
  int t = __builtin_amdgcn_update_dpp(0, __float_as_int(v), CTRL, 0xF, 0xF, true);
  return v + __int_as_float(t);
}
// Hardened permlane sums (R3 lesson: tied-operand aliasing) — distinct
// early-clobber second reg initialized inside the asm.
__device__ __forceinline__ float pl16sum(float v) {
  float a = v, b;
  asm("v_mov_b32 %1, %0\n\t"
      "v_permlane16_swap_b32 %0, %1"
      : "+v"(a), "=&v"(b));
  return a + b;
}
__device__ __forceinline__ float pl32sum(float v) {
  float a = v, b;
  asm("v_mov_b32 %1, %0\n\t"
      "v_permlane32_swap_b32 %0, %1"
      : "+v"(a), "=&v"(b));
  return a + b;
}

// Block = 32 j x 8 b per tile, 5 tiles per block (grid 8 x 125) — R12 champion
// restored. R14 lesson: XOR bank-swizzle on s_h/s_pair fixed P6's conflicts
// (3.89M->2.29M) but the extra addressing state pushed VGPR demand past the
// 128 cap -> ~22MB scratch spill, pe_fused 93->113 us. At this register
// pressure the conflicts (~3-4 us) are cheaper than any fix found; register
// budget is the binding constraint. R12 features: prefetch split (nf2/nf3
// loaded after P6), setprio around P4/P5 compute clusters (T5).
// R11 lesson: cooperative launch rejected at 1000 blocks. R10: serial
// pre-kernel launch overhead > dedup saving. R2: never bound below need.
__global__ __launch_bounds__(256, 2) void pe_fused(
    const float* __restrict__ x, const int* __restrict__ mask,
    const int* __restrict__ atse_idx, const float* __restrict__ fe,
    const float* __restrict__ ae,
    const float* __restrict__ hW1, const float* __restrict__ hb1,
    const float* __restrict__ hl1g, const float* __restrict__ hl1b,
    const float* __restrict__ hW2, const float* __restrict__ hb2,
    const float* __restrict__ hl2g, const float* __restrict__ hl2b,
    const float* __restrict__ gW1, const float* __restrict__ gb1,
    const float* __restrict__ gW2, const float* __restrict__ gb2,
    float* __restrict__ acc_g, float* __restrict__ se_g) {
  __shared__ __align__(16) float s_pg[32 * 68];      // pre1; cols 64..67 = ex scratch
  __shared__ __align__(16) float s_gb[32 * 24 + 16]; // gate bias per j
  __shared__ __align__(16) float s_pair[256 * 4];    // pair scalars / e; prologue: gW1bf
  __shared__ __align__(16) float s_ae[32 * 20];      // ae rows (dedicated)
  __shared__ __align__(16) float s_w0[64], s_w0g[64], s_l1g[64], s_l1b[64];
  __shared__ __align__(16) float s_b2[32], s_l2g[32], s_l2b[32];
  __shared__ __align__(16) float s_gb1[24], s_gW2[96];
  __shared__ float s_gb2[4], s_scal[2];
  __shared__ __align__(16) float s_gW1aT[24 * 16];   // gW1 ae-part, [c][a] transposed
  __shared__ unsigned char s_mk[256];
  __shared__ __align__(16) unsigned short s_ovl[256 * 36];  // s_h bf16 [256][36]

  int tid = threadIdx.x;
  int btile = blockIdx.x;   // 0..7
  int ytile = blockIdx.y;   // 0..124
  int lane = tid & 63, wv = tid >> 6;
  int li = lane & 15, quad = lane >> 4;
  unsigned short* s_h = s_ovl;
  unsigned short* s_gW1bf = (unsigned short*)s_pair;  // prologue-only overlay

  // ---------------- prologue: stage persistent weights ----------------
  for (int i = tid; i < 768; i += 256) s_gW1bf[i] = f2bf(gW1[i]);
  for (int i = tid; i < 384; i += 256)
    s_gW1aT[i] = gW1[768 + (i & 15) * 24 + (i >> 4)];
  if (tid < 96) s_gW2[tid] = gW2[tid];
  if (tid < 64) { s_w0[tid] = hW1[tid]; s_l1g[tid] = hl1g[tid]; s_l1b[tid] = hl1b[tid]; }
  if (tid < 32) { s_b2[tid] = hb2[tid]; s_l2g[tid] = hl2g[tid]; s_l2b[tid] = hl2b[tid]; }
  if (tid < 24) s_gb1[tid] = gb1[tid];
  if (tid < 4) s_gb2[tid] = gb2[tid];
  if (tid >= 224 && tid < 240) s_gb[32 * 24 + (tid - 224)] = 0.f;  // overhang zeros

  // per-thread register fragments (j-independent)
  short8 bW2[2][2];
#pragma unroll
  for (int kt = 0; kt < 2; ++kt)
#pragma unroll
    for (int nt = 0; nt < 2; ++nt) {
      U8 t;
#pragma unroll
      for (int p = 0; p < 4; ++p) {
        float lo = hW2[(kt * 32 + quad * 8 + 2 * p) * 32 + nt * 16 + li];
        float hi = hW2[(kt * 32 + quad * 8 + 2 * p + 1) * 32 + nt * 16 + li];
        t.u[p] = pkbf(lo, hi);
      }
      bW2[kt][nt] = t.s;
    }
  U8 bH;
#pragma unroll
  for (int p = 0; p < 4; ++p) {
    float lo = hW1[(1 + quad * 8 + 2 * p) * 64 + wv * 16 + li];
    float hi = hW1[(1 + quad * 8 + 2 * p + 1) * 64 + wv * 16 + li];
    bH.u[p] = pkbf(lo, hi);
  }
  float hb = hb1[wv * 16 + li];

  __syncthreads();
  if (tid < 64) s_w0g[tid] = s_w0[tid] * s_l1g[tid];
  if (tid == 64) {
    float sw = 0.f, qw = 0.f;
    for (int k = 0; k < 64; ++k) { float w = s_w0[k]; sw += w; qw = fmaf(w, w, qw); }
    s_scal[0] = sw; s_scal[1] = qw;
  }
  // gate A-frags from s_gW1bf overlay (read pre-bar1; s_pair written post-bar1)
  short8 aG0, aG1;
#pragma unroll
  for (int i = 0; i < 8; ++i) {
    int k = quad * 8 + i;
    aG0[i] = (short)s_gW1bf[k * 24 + li];
    aG1[i] = (li < 8) ? (short)s_gW1bf[k * 24 + 16 + li] : (short)0;
  }

  f32x4 racc[2][2];
#pragma unroll
  for (int a = 0; a < 2; ++a)
#pragma unroll
    for (int c = 0; c < 2; ++c) {
      racc[a][c][0] = 0.f; racc[a][c][1] = 0.f; racc[a][c][2] = 0.f; racc[a][c][3] = 0.f;
    }
  float seacc[2] = {0.f, 0.f};

  int jp8 = tid >> 3, b8 = tid & 7;
  int J0 = ytile * ITERS * 32;
  float xv; int mk;

  // ---------------- A(0): ae gather + x/mask + pre1 MFMA ----------------
  {
    if (tid < 128) {
      int jj = tid >> 2, q = tid & 3;
      int ai = atse_idx[J0 + jj];
      float4 av = *(const float4*)(ae + (size_t)ai * 16 + q * 4);
      *(float4*)(s_ae + jj * 20 + q * 4) = av;
    }
    size_t xo = (size_t)(btile * 8 + b8) * Jv + J0 + jp8;
    xv = x[xo];
    mk = mask[xo];
    f32x4 cP;
#pragma unroll
    for (int mt = 0; mt < 2; ++mt) {
      cP[0] = hb; cP[1] = hb; cP[2] = hb; cP[3] = hb;
      const float* fp = fe + (size_t)(J0 + mt * 16 + li) * 32 + quad * 8;
      float4 f0 = *(const float4*)fp;
      float4 f1 = *(const float4*)(fp + 4);
      U8 aF;
      aF.u[0] = pkbf(f0.x, f0.y); aF.u[1] = pkbf(f0.z, f0.w);
      aF.u[2] = pkbf(f1.x, f1.y); aF.u[3] = pkbf(f1.z, f1.w);
      cP = __builtin_amdgcn_mfma_f32_16x16x32_bf16(aF.s, bH.s, cP, 0, 0, 0);
#pragma unroll
      for (int r = 0; r < 4; ++r)
        s_pg[(mt * 16 + quad * 4 + r) * 68 + wv * 16 + li] = cP[r];
    }
  }
  __syncthreads();  // bar1

  for (int it = 0; it < ITERS; ++it) {
    // -------- B: gate bias + stats + pair scalars + P4 + P5 --------
    {
      int c0 = b8 * 3;
      const f32x2* ar2 = (const f32x2*)(s_ae + jp8 * 20);
      f32x2 A[8];
#pragma unroll
      for (int a = 0; a < 8; ++a) A[a] = ar2[a];
#pragma unroll
      for (int c = 0; c < 3; ++c) {
        const f32x2* tr2 = (const f32x2*)(s_gW1aT + (c0 + c) * 16);
        f32x2 g2 = {s_gb1[c0 + c], 0.f};
#pragma unroll
        for (int a = 0; a < 8; ++a) g2 = pk_fma(A[a], tr2[a], g2);
        s_gb[jp8 * 24 + c0 + c] = g2.x + g2.y;
      }
    }
    {
      const f32x2* pp2 = (const f32x2*)(s_pg + jp8 * 68 + b8 * 8);
      const f32x2* ww2 = (const f32x2*)(s_w0 + b8 * 8);
      f32x2 p2[4] = {pp2[0], pp2[1], pp2[2], pp2[3]};
      f32x2 s2 = (p2[0] + p2[1]) + (p2[2] + p2[3]);
      f32x2 q2 = pk_fma(p2[0], p2[0],
                 pk_fma(p2[1], p2[1],
                 pk_fma(p2[2], p2[2], p2[3] * p2[3])));
      f32x2 d2 = pk_fma(p2[0], ww2[0],
                 pk_fma(p2[1], ww2[1],
                 pk_fma(p2[2], ww2[2], p2[3] * ww2[3])));
      float sp = s2.x + s2.y, qp = q2.x + q2.y, dwp = d2.x + d2.y;
      sp = dppadd<0xB1>(sp); sp = dppadd<0x4E>(sp); sp = dppadd<0x141>(sp);
      qp = dppadd<0xB1>(qp); qp = dppadd<0x4E>(qp); qp = dppadd<0x141>(qp);
      dwp = dppadd<0xB1>(dwp); dwp = dppadd<0x4E>(dwp); dwp = dppadd<0x141>(dwp);
      if (b8 == 0) *(float4*)(s_pg + jp8 * 68 + 64) = make_float4(sp, qp, dwp, 0.f);
    }
    {
      float4 exv = *(const float4*)(s_pg + jp8 * 68 + 64);
      float mu1 = fmaf(xv, s_scal[0], exv.x) * 0.015625f;
      float Et2 = fmaf(xv * xv, s_scal[1], fmaf(2.0f * xv, exv.z, exv.y)) * 0.015625f;
      float rs1 = rsqrtf(fmaxf(Et2 - mu1 * mu1, 0.f) + 1e-5f);
      *(float4*)(s_pair + tid * 4) = make_float4(xv * rs1, rs1, -mu1 * rs1, 0.f);
      s_mk[tid] = (unsigned char)mk;
    }

    // P4: a-frags -> MFMA h2 -> LN2 -> s_h
    {
      f32x4 cd[4][2];
      float b2a = s_b2[li], b2b = s_b2[16 + li];
#pragma unroll
      for (int t = 0; t < 4; ++t) {
        cd[t][0][0] = b2a; cd[t][0][1] = b2a; cd[t][0][2] = b2a; cd[t][0][3] = b2a;
        cd[t][1][0] = b2b; cd[t][1][1] = b2b; cd[t][1][2] = b2b; cd[t][1][3] = b2b;
      }
      __builtin_amdgcn_s_setprio(1);  // T5: favor compute cluster vs other blocks
#pragma unroll
      for (int kt = 0; kt < 2; ++kt) {
        int base = kt * 32 + quad * 8;
        float4 wg0 = *(const float4*)(s_w0g + base);
        float4 wg1 = *(const float4*)(s_w0g + base + 4);
        float4 gg0 = *(const float4*)(s_l1g + base);
        float4 gg1 = *(const float4*)(s_l1g + base + 4);
        float4 bb0 = *(const float4*)(s_l1b + base);
        float4 bb1 = *(const float4*)(s_l1b + base + 4);
        f32x2 wg2[4] = {{wg0.x, wg0.y}, {wg0.z, wg0.w}, {wg1.x, wg1.y}, {wg1.z, wg1.w}};
        f32x2 gg2[4] = {{gg0.x, gg0.y}, {gg0.z, gg0.w}, {gg1.x, gg1.y}, {gg1.z, gg1.w}};
        f32x2 bb2[4] = {{bb0.x, bb0.y}, {bb0.z, bb0.w}, {bb1.x, bb1.y}, {bb1.z, bb1.w}};
#pragma unroll
        for (int t = 0; t < 4; ++t) {
          int mrow = wv * 64 + t * 16 + li;
          float4 pr = *(const float4*)(s_pair + mrow * 4);
          f32x2 prx = {pr.x, pr.x}, pry = {pr.y, pr.y}, prz = {pr.z, pr.z};
          const float* pgp = s_pg + (mrow >> 3) * 68 + base;
          float4 p0 = *(const float4*)pgp;
          float4 p1 = *(const float4*)(pgp + 4);
          f32x2 pv2[4] = {{p0.x, p0.y}, {p0.z, p0.w}, {p1.x, p1.y}, {p1.z, p1.w}};
          U8 a8;
#pragma unroll
          for (int i = 0; i < 4; ++i) {
            f32x2 av2 = pk_max0(pk_fma(pk_fma(pry, pv2[i], prz), gg2[i],
                                       pk_fma(prx, wg2[i], bb2[i])));
            a8.u[i] = pkbf(av2.x, av2.y);
          }
          cd[t][0] = __builtin_amdgcn_mfma_f32_16x16x32_bf16(a8.s, bW2[kt][0], cd[t][0], 0, 0, 0);
          cd[t][1] = __builtin_amdgcn_mfma_f32_16x16x32_bf16(a8.s, bW2[kt][1], cd[t][1], 0, 0, 0);
        }
      }
      __builtin_amdgcn_s_setprio(0);
      float g0 = s_l2g[li], be0 = s_l2b[li];
      float g1v = s_l2g[16 + li], be1 = s_l2b[16 + li];
#pragma unroll
      for (int t = 0; t < 4; ++t) {
        float sum[4], sq[4];
#pragma unroll
        for (int r = 0; r < 4; ++r) {
          float a = cd[t][0][r], b = cd[t][1][r];
          sum[r] = a + b;
          sq[r] = fmaf(a, a, b * b);
        }
#pragma unroll
        for (int r = 0; r < 4; ++r) {
          sum[r] = dppadd<0xB1>(sum[r]); sum[r] = dppadd<0x4E>(sum[r]);
          sum[r] = dppadd<0x124>(sum[r]); sum[r] = dppadd<0x128>(sum[r]);
          sq[r] = dppadd<0xB1>(sq[r]); sq[r] = dppadd<0x4E>(sq[r]);
          sq[r] = dppadd<0x124>(sq[r]); sq[r] = dppadd<0x128>(sq[r]);
        }
#pragma unroll
        for (int r = 0; r < 4; ++r) {
          float mu = sum[r] * 0.03125f;
          float var = sq[r] * 0.03125f - mu * mu;
          float rs2 = rsqrtf(fmaxf(var, 0.f) + 1e-5f);
          int m = wv * 64 + t * 16 + quad * 4 + r;
          float h0 = fmaxf(fmaf((cd[t][0][r] - mu) * rs2, g0, be0), 0.f);
          float h1 = fmaxf(fmaf((cd[t][1][r] - mu) * rs2, g1v, be1), 0.f);
          s_h[m * 36 + li] = f2bf(h0);
          s_h[m * 36 + 16 + li] = f2bf(h1);
        }
      }
    }
    // no barrier: P5 touches only own-wave rows (in-order DS)

    // P5: gate via MFMA + packed combine + permlane quad-reduce
    {
      float4 gw4[2][4];
#pragma unroll
      for (int mt = 0; mt < 2; ++mt)
#pragma unroll
        for (int r = 0; r < 4; ++r) {
          int c = mt * 16 + quad * 4 + r;
          gw4[mt][r] = (c < 24) ? ((const float4*)s_gW2)[c]
                                : make_float4(0.f, 0.f, 0.f, 0.f);
        }
      __builtin_amdgcn_s_setprio(1);
#pragma unroll
      for (int nt = 0; nt < 4; ++nt) {
        int m = wv * 64 + nt * 16 + li;
        U8 bu;
        const u32x2* hp2 = (const u32x2*)(s_h + m * 36 + quad * 8);  // 8B aligned
        u32x2 h01 = hp2[0], h23 = hp2[1];
        bu.u[0] = h01[0]; bu.u[1] = h01[1]; bu.u[2] = h23[0]; bu.u[3] = h23[1];
        int j = m >> 3;
        float4 cc0 = *(const float4*)(s_gb + j * 24 + quad * 4);
        float4 cc1 = *(const float4*)(s_gb + j * 24 + 16 + quad * 4);
        f32x4 c0, c1;
        c0[0] = cc0.x; c0[1] = cc0.y; c0[2] = cc0.z; c0[3] = cc0.w;
        c1[0] = cc1.x; c1[1] = cc1.y; c1[2] = cc1.z; c1[3] = cc1.w;
        c0 = __builtin_amdgcn_mfma_f32_16x16x32_bf16(aG0, bu.s, c0, 0, 0, 0);
        c1 = __builtin_amdgcn_mfma_f32_16x16x32_bf16(aG1, bu.s, c1, 0, 0, 0);
        f32x2 r01 = {s_gb2[0], s_gb2[1]};
        f32x2 r23 = {s_gb2[2], s_gb2[3]};
#pragma unroll
        for (int r = 0; r < 4; ++r) {
          float v0 = fmaxf(c0[r], 0.f);
          float v1 = fmaxf(c1[r], 0.f);
          f32x2 v0b = {v0, v0}, v1b = {v1, v1};
          float4 ga = gw4[0][r], gb = gw4[1][r];
          f32x2 ga01 = {ga.x, ga.y}, ga23 = {ga.z, ga.w};
          f32x2 gb01 = {gb.x, gb.y}, gb23 = {gb.z, gb.w};
          r01 = pk_fma(v0b, ga01, pk_fma(v1b, gb01, r01));
          r23 = pk_fma(v0b, ga23, pk_fma(v1b, gb23, r23));
        }
        float r0 = pl32sum(pl16sum(r01.x));
        float r1 = pl32sum(pl16sum(r01.y));
        float r2 = pl32sum(pl16sum(r23.x));
        float r3 = pl32sum(pl16sum(r23.y));
        r0 = fminf(fmaxf(r0, -10.f), 10.f);
        r1 = fminf(fmaxf(r1, -10.f), 10.f);
        r2 = fminf(fmaxf(r2, -10.f), 10.f);
        r3 = fminf(fmaxf(r3, -10.f), 10.f);
        bool act = (s_mk[m] != 0);
        float e0 = act ? __expf(r0 - 10.f) : 0.f;
        float e1 = act ? __expf(r1 - 10.f) : 0.f;
        float e2 = act ? __expf(r2 - 10.f) : 0.f;
        float e3 = act ? __expf(r3 - 10.f) : 0.f;
        if (quad == 0) *(float4*)(s_pair + m * 4) = make_float4(e0, e1, e2, e3);
      }
      __builtin_amdgcn_s_setprio(0);
    }
    __syncthreads();  // bar2: e + s_h visible cross-wave

    // -------- P6(t) with A(t+1) pipelined into the slot --------
    // Prefetch split: nf0/nf1+ae+x/mask before P6; nf2/nf3 after P6
    // (overlap s_ae write + mt=0 MFMA) -> 8 fewer live VGPRs across P6.
    bool has_next = (it + 1 < ITERS);
    int J0n = J0 + 32;
    float4 nf0, nf1, nav;
    float nxv = 0.f; int nmk = 0;
    if (has_next) {
      if (tid < 128) {
        int jj = tid >> 2, q = tid & 3;
        int ai = atse_idx[J0n + jj];
        nav = *(const float4*)(ae + (size_t)ai * 16 + q * 4);
      }
      const float* fp0 = fe + (size_t)(J0n + li) * 32 + quad * 8;
      nf0 = *(const float4*)fp0; nf1 = *(const float4*)(fp0 + 4);
      size_t xo = (size_t)(btile * 8 + b8) * Jv + J0n + jp8;
      nxv = x[xo];
      nmk = mask[xo];
    }
    // P6: e-h reduce via MFMA, accumulate in registers (wave handles 2 b's)
    {
      const float* s_e2 = s_pair;
#pragma unroll
      for (int bs = 0; bs < 2; ++bs) {
        int b = wv * 2 + bs;
        float ev[8];
        float sep = 0.f;
#pragma unroll
        for (int i = 0; i < 8; ++i) {
          float v = s_e2[((quad * 8 + i) * 8 + b) * 4 + (li & 3)];
          v = (li < 4) ? v : 0.f;
          ev[i] = v;
          sep += v;
        }
        seacc[bs] += sep;
        U8 a8;
        a8.u[0] = pkbf(ev[0], ev[1]); a8.u[1] = pkbf(ev[2], ev[3]);
        a8.u[2] = pkbf(ev[4], ev[5]); a8.u[3] = pkbf(ev[6], ev[7]);
#pragma unroll
        for (int half = 0; half < 2; ++half) {
          U8 bh;
#pragma unroll
          for (int p = 0; p < 4; ++p) {
            unsigned int lo = s_h[((quad * 8 + 2 * p) * 8 + b) * 36 + half * 16 + li];
            unsigned int hi = s_h[((quad * 8 + 2 * p + 1) * 8 + b) * 36 + half * 16 + li];
            bh.u[p] = lo | (hi << 16);
          }
          racc[bs][half] = __builtin_amdgcn_mfma_f32_16x16x32_bf16(a8.s, bh.s, racc[bs][half], 0, 0, 0);
        }
      }
    }
    if (has_next) {
      if (tid < 128) {
        int jj = tid >> 2, q = tid & 3;
        *(float4*)(s_ae + jj * 20 + q * 4) = nav;
      }
      // issue second fe half now; latency overlaps s_ae write + mt=0 MFMA
      const float* fp1 = fe + (size_t)(J0n + 16 + li) * 32 + quad * 8;
      float4 nf2 = *(const float4*)fp1;
      float4 nf3 = *(const float4*)(fp1 + 4);
      f32x4 cP;
#pragma unroll
      for (int mt = 0; mt < 2; ++mt) {
        cP[0] = hb; cP[1] = hb; cP[2] = hb; cP[3] = hb;
        U8 aF;
        if (mt == 0) {
          aF.u[0] = pkbf(nf0.x, nf0.y); aF.u[1] = pkbf(nf0.z, nf0.w);
          aF.u[2] = pkbf(nf1.x, nf1.y); aF.u[3] = pkbf(nf1.z, nf1.w);
        } else {
          aF.u[0] = pkbf(nf2.x, nf2.y); aF.u[1] = pkbf(nf2.z, nf2.w);
          aF.u[2] = pkbf(nf3.x, nf3.y); aF.u[3] = pkbf(nf3.z, nf3.w);
        }
        cP = __builtin_amdgcn_mfma_f32_16x16x32_bf16(aF.s, bH.s, cP, 0, 0, 0);
#pragma unroll
        for (int r = 0; r < 4; ++r)
          s_pg[(mt * 16 + quad * 4 + r) * 68 + wv * 16 + li] = cP[r];
      }
      xv = nxv; mk = nmk;
      J0 = J0n;
      __syncthreads();  // bar3: A(t+1) visible + P6(t) reads done
    }
  }

  // ---------------- flush: one atomic pass per block ----------------
#pragma unroll
  for (int bs = 0; bs < 2; ++bs) {
    float se = seacc[bs];
    se = pl32sum(pl16sum(se));
    if (quad == 0) {
      int bg = btile * 8 + wv * 2 + bs;
      float* dst = acc_g + (size_t)bg * 128;
#pragma unroll
      for (int half = 0; half < 2; ++half)
#pragma unroll
        for (int r = 0; r < 4; ++r)
          atomicAdd(dst + r * 32 + half * 16 + li, racc[bs][half][r]);
      if (li < 4) atomicAdd(&se_g[bg * 4 + li], se);
    }
  }
}

// ---------------- per-b tail (R8): 256 threads, parallel matvecs ----------
__global__ __launch_bounds__(256) void pe_tail(
    const float* __restrict__ acc_g, const float* __restrict__ se_g,
    const float* __restrict__ cW, const float* __restrict__ cb,
    const float* __restrict__ clng, const float* __restrict__ clnb,
    const float* __restrict__ eW1, const float* __restrict__ eb1,
    const float* __restrict__ eW2, const float* __restrict__ eb2,
    float* __restrict__ out) {
  int b = blockIdx.x;
  int tid = threadIdx.x;
  __shared__ float s_hs[128], s_cp[32], s_comb[32], s_e1[128], s_o2[64];
  __shared__ float s_red[4];

  float se0 = se_g[b * 4 + 0];
  bool empty = !(se0 > 0.0f);
  if (tid < 128) {
    float sw = se_g[b * 4 + (tid >> 5)];
    float inv = empty ? 0.0f : 1.0f / sw;
    s_hs[tid] = acc_g[b * 128 + tid] * inv;
  }
  __syncthreads();

  // c-layer: 32 outputs x 128 terms; 8 threads/output, 16 terms each
  {
    int o = tid >> 3, seg = tid & 7;
    float p = 0.f;
#pragma unroll
    for (int i = 0; i < 16; ++i) {
      int k = seg * 16 + i;
      p = fmaf(s_hs[k], cW[k * 32 + o], p);
    }
    p += __shfl_xor(p, 1);
    p += __shfl_xor(p, 2);
    p += __shfl_xor(p, 4);
    if (seg == 0) s_cp[o] = p + cb[o];
  }
  __syncthreads();

  // c LN (affine) + relu over 32 outputs (lanes 0..31 of wave 0)
  if (tid < 32) {
    float cp = s_cp[tid];
    float ssum = cp;
#pragma unroll
    for (int off = 16; off > 0; off >>= 1) ssum += __shfl_xor(ssum, off, 32);
    float mu = ssum * (1.0f / 32.0f);
    float dd = cp - mu;
    float sq = dd * dd;
#pragma unroll
    for (int off = 16; off > 0; off >>= 1) sq += __shfl_xor(sq, off, 32);
    float rs = rsqrtf(sq * (1.0f / 32.0f) + 1e-5f);
    float comb = fmaxf(fmaf(dd * rs, clng[tid], clnb[tid]), 0.0f);
    if (empty) comb = 0.0f;
    s_comb[tid] = comb;
  }
  __syncthreads();

  // e1: 128 outputs x 32 terms; one thread per output (tid<128)
  float v1 = 0.f;
  if (tid < 128) {
    v1 = eb1[tid];
#pragma unroll
    for (int i = 0; i < 32; ++i) v1 = fmaf(s_comb[i], eW1[i * 128 + tid], v1);
    float ss = v1, sq = v1 * v1;
#pragma unroll
    for (int off = 32; off > 0; off >>= 1) {
      ss += __shfl_xor(ss, off);
      sq += __shfl_xor(sq, off);
    }
    if ((tid & 63) == 0) {
      s_red[(tid >> 6) * 2] = ss;
      s_red[(tid >> 6) * 2 + 1] = sq;
    }
  }
  __syncthreads();
  if (tid < 128) {
    float ssT = s_red[0] + s_red[2];
    float sqT = s_red[1] + s_red[3];
    float mu = ssT * (1.0f / 128.0f);
    float var = sqT * (1.0f / 128.0f) - mu * mu;
    float rs = rsqrtf(fmaxf(var, 0.f) + 1e-5f);
    s_e1[tid] = fmaxf((v1 - mu) * rs, 0.0f);
  }
  __syncthreads();

  // e2: 64 outputs x 128 terms; 4 threads/output, 32 terms each
  {
    int o = tid >> 2, sg = tid & 3;
    float v = 0.f;
#pragma unroll
    for (int i = 0; i < 32; ++i) {
      int k = sg * 32 + i;
      v = fmaf(s_e1[k], eW2[k * 64 + o], v);
    }
    v += __shfl_xor(v, 1);
    v += __shfl_xor(v, 2);
    if (sg == 0) s_o2[o] = v + eb2[o];
  }
  __syncthreads();

  // final LN (no affine) + relu over 64 + store (wave 0)
  if (tid < 64) {
    float v = s_o2[tid];
    float ss = v, sq = v * v;
#pragma unroll
    for (int off = 32; off > 0; off >>= 1) {
      ss += __shfl_xor(ss, off);
      sq += __shfl_xor(sq, off);
    }
    float mu = ss * (1.0f / 64.0f);
    float var = sq * (1.0f / 64.0f) - mu * mu;
    float rs = rsqrtf(fmaxf(var, 0.f) + 1e-5f);
    float o = fmaxf((v - mu) * rs, 0.0f);
    if (tid < 32)
      out[b * 32 + tid] = o;                       // mu
    else
      out[Bv * 32 + b * 32 + (tid - 32)] = o;      // logvar
  }
}

extern "C" void kernel_launch(void* const* d_in, const int* in_sizes, int n_in,
                              void* d_out, int out_size, void* d_ws, size_t ws_size,
                              hipStream_t stream) {
  const float* x    = (const float*)d_in[0];
  const int* mask   = (const int*)d_in[1];
  const int* atse   = (const int*)d_in[2];
  const float* fe   = (const float*)d_in[3];
  const float* ae   = (const float*)d_in[4];
  const float* hW1  = (const float*)d_in[5];
  const float* hb1  = (const float*)d_in[6];
  const float* hl1g = (const float*)d_in[7];
  const float* hl1b = (const float*)d_in[8];
  const float* hW2  = (const float*)d_in[9];
  const float* hb2  = (const float*)d_in[10];
  const float* hl2g = (const float*)d_in[11];
  const float* hl2b = (const float*)d_in[12];
  const float* gW1  = (const float*)d_in[13];
  const float* gb1  = (const float*)d_in[14];
  const float* gW2  = (const float*)d_in[15];
  const float* gb2  = (const float*)d_in[16];
  const float* cW   = (const float*)d_in[17];
  const float* cb   = (const float*)d_in[18];
  const float* clng = (const float*)d_in[19];
  const float* clnb = (const float*)d_in[20];
  const float* eW1  = (const float*)d_in[21];
  const float* eb1  = (const float*)d_in[22];
  const float* eW2  = (const float*)d_in[23];
  const float* eb2  = (const float*)d_in[24];
  float* out = (float*)d_out;

  float* ws = (float*)d_ws;
  float* accg = ws;                 // B*128 floats
  float* seg  = accg + Bv * 128;    // B*4 floats

  hipMemsetAsync(accg, 0, (Bv * 128 + Bv * 4) * sizeof(float), stream);

  pe_fused<<<dim3(NBT, NYB), dim3(256), 0, stream>>>(
      x, mask, atse, fe, ae, hW1, hb1, hl1g, hl1b, hW2, hb2, hl2g, hl2b,
      gW1, gb1, gW2, gb2, accg, seg);
  pe_tail<<<dim3(Bv), dim3(256), 0, stream>>>(
      accg, seg, cW, cb, clng, clnb, eW1, eb1, eW2, eb2, out);
}